// Round 3
// baseline (473.480 us; speedup 1.0000x reference)
//
#include <hip/hip_runtime.h>

#define NB   8
#define BKK  288
#define CWW  1152
#define HH   17
#define EPSF 1e-10f
#define ICH  16           // i-chunks for mpart partials
#define ISZ  18           // BKK/ICH
#define JT   18           // CWW/64 j-tiles
#define ECH  8            // i-rows per estep block
#define NECH 36           // BKK/ECH
#define SCALE      65536.f
#define INV_SCALE  (1.f/65536.f)
#define INV_SCALE2 (1.f/65536.f/65536.f)

// 4-aligned float4 (records are 17 floats; CDNA dwordx4 needs only dword align)
struct __attribute__((aligned(4))) f4u { float x, y, z, w; };
// 8-aligned ushort4 (vu16 records are 16 u16 = 32B, h4-chunks 8B-aligned)
struct __attribute__((aligned(8))) us4 { unsigned short x, y, z, w; };
typedef float v4f __attribute__((ext_vector_type(4)));

// params per (b,j): [0..15]=mu*2^16, [16..31]=(0.5/sigsq)*2^-32,
//                   [32..47]=a*rsqrt(2pi)/(sig+eps)*exp(-eps*0.5/sigsq)

// iter0 M-step: reads fp32 votes once; emits u16 votes + u16 a + partials.
// (passthrough copy moved to its own streaming kernel)
__global__ __launch_bounds__(256) void mpart0_kernel(
    const float* __restrict__ votes,
    unsigned short* __restrict__ vu16,
    unsigned short* __restrict__ au16,
    float* __restrict__ p12,
    float* __restrict__ p0)
{
    const int x  = blockIdx.x;
    const int jt = x % JT;
    const int c  = (x / JT) % ICH;
    const int b  = x / (JT * ICH);
    const int t  = threadIdx.x;
    const int jl = t >> 2;               // 0..63
    const int h4 = t & 3;
    const int i0 = c * ISZ;

    const size_t rowe = (size_t)CWW * HH;
    const float* base = votes + ((size_t)b * BKK + i0) * rowe + jt * (64 * HH);
    const int voff = jl * HH + h4 * 4;
    const int aoff = jl * HH + 16;
    const size_t dbase = ((size_t)b * BKK + i0) * CWW + jt * 64 + jl;

    float s0 = 0.f;
    float s1x=0.f,s1y=0.f,s1z=0.f,s1w=0.f;
    float s2x=0.f,s2y=0.f,s2z=0.f,s2w=0.f;

    #pragma unroll 6
    for (int i = 0; i < ISZ; i++) {
        const float* rec = base + (size_t)i * rowe;
        f4u v = *(const f4u*)(rec + voff);
        float a16 = rec[aoff];

        // u16 fixed-point quantize (error <= 2^-17; clamp avoids 65536 wrap)
        unsigned int ux = (unsigned int)(fminf(v.x * SCALE, 65535.f) + 0.5f);
        unsigned int uy = (unsigned int)(fminf(v.y * SCALE, 65535.f) + 0.5f);
        unsigned int uz = (unsigned int)(fminf(v.z * SCALE, 65535.f) + 0.5f);
        unsigned int uw = (unsigned int)(fminf(v.w * SCALE, 65535.f) + 0.5f);
        us4 us = { (unsigned short)ux, (unsigned short)uy,
                   (unsigned short)uz, (unsigned short)uw };
        *(us4*)(vu16 + (dbase + (size_t)i * CWW) * 16 + h4 * 4) = us;
        if (h4 == 0) {
            unsigned int ua = (unsigned int)(fminf(a16 * SCALE, 65535.f) + 0.5f);
            au16[dbase + (size_t)i * CWW] = (unsigned short)ua;
        }

        // accumulate in u-space (exact cvt; rescaled once in mfin)
        float fx = (float)ux, fy = (float)uy, fz = (float)uz, fw = (float)uw;
        float rt = a16 * (1.f / 32.f);
        s0 += rt;
        s1x += rt*fx; s2x += rt*fx*fx;
        s1y += rt*fy; s2y += rt*fy*fy;
        s1z += rt*fz; s2z += rt*fz*fz;
        s1w += rt*fw; s2w += rt*fw*fw;
    }

    const int j = jt * 64 + jl;
    float* o = p12 + (((size_t)(b * CWW + j)) * ICH + c) * 32 + h4 * 4;
    *(float4*)o        = make_float4(s1x, s1y, s1z, s1w);
    *(float4*)(o + 16) = make_float4(s2x, s2y, s2z, s2w);
    if (h4 == 0) p0[((size_t)(b * CWW + j)) * ICH + c] = s0;
}

// iters 1,2 M-step: u16 votes/a, inline rsinv from psum (rowsum folded in).
__global__ __launch_bounds__(256) void mpart12_kernel(
    const unsigned short* __restrict__ vu16,
    const unsigned short* __restrict__ au16,
    const float* __restrict__ p_arr,
    const float* __restrict__ psum,      // [b,i,JT] partial row sums
    float* __restrict__ p12,
    float* __restrict__ p0,
    float* __restrict__ r_out)           // iter2: R_out = (p*rsinv+eps)*a_
{
    __shared__ float rsv[ISZ];
    const int x  = blockIdx.x;
    const int jt = x % JT;
    const int c  = (x / JT) % ICH;
    const int b  = x / (JT * ICH);
    const int t  = threadIdx.x;
    const int jl = t >> 2;
    const int h4 = t & 3;
    const int i0 = c * ISZ;
    const int bi0 = b * BKK + i0;

    if (t < ISZ) {
        const float* ps = psum + (size_t)(bi0 + t) * JT;
        float s = 0.f;
        #pragma unroll
        for (int k = 0; k < JT; k++) s += ps[k];
        rsv[t] = 1.f / (s + EPSF);
    }
    __syncthreads();

    const size_t dbase = (size_t)bi0 * CWW + jt * 64 + jl;
    const unsigned short* vbase = vu16 + dbase * 16 + h4 * 4;

    float s0 = 0.f;
    float s1x=0.f,s1y=0.f,s1z=0.f,s1w=0.f;
    float s2x=0.f,s2y=0.f,s2z=0.f,s2w=0.f;

    #pragma unroll 6
    for (int i = 0; i < ISZ; i++) {
        us4 u = *(const us4*)(vbase + (size_t)i * (CWW * 16));
        float pv = p_arr[dbase + (size_t)i * CWW];
        float av = (float)au16[dbase + (size_t)i * CWW] * INV_SCALE;
        float ri = rsv[i];
        float rr = fmaf(pv, ri, EPSF);          // R update (pre a_)
        float rt = rr * av;                      // reference's R*a_
        float fx = (float)u.x, fy = (float)u.y, fz = (float)u.z, fw = (float)u.w;
        s0 += rt;
        s1x += rt*fx; s2x += rt*fx*fx;
        s1y += rt*fy; s2y += rt*fy*fy;
        s1z += rt*fz; s2z += rt*fz*fz;
        s1w += rt*fw; s2w += rt*fw*fw;
        // reference returns R after the top-of-iter2 reassignment:
        // (p*rsinv+eps)*a_
        if (r_out && h4 == 0)
            __builtin_nontemporal_store(rt, r_out + dbase + (size_t)i * CWW);
    }

    const int j = jt * 64 + jl;
    float* o = p12 + (((size_t)(b * CWW + j)) * ICH + c) * 32 + h4 * 4;
    *(float4*)o        = make_float4(s1x, s1y, s1z, s1w);
    *(float4*)(o + 16) = make_float4(s2x, s2y, s2z, s2w);
    if (h4 == 0) p0[((size_t)(b * CWW + j)) * ICH + c] = s0;
}

__global__ __launch_bounds__(256) void mfin_kernel(
    const float* __restrict__ p12,
    const float* __restrict__ p0,
    const float* __restrict__ beta_v,
    const float* __restrict__ beta_a,
    float* __restrict__ params,          // non-final iters
    float* __restrict__ out_mua)         // final iter (params == null)
{
    const int wid  = (blockIdx.x * 256 + threadIdx.x) >> 6;   // b*1152+j
    const int lane = threadIdx.x & 63;
    const int h    = lane & 15;
    const int q    = lane >> 4;
    const int b    = wid / CWW;
    const int j    = wid - b * CWW;
    (void)b;

    float s0 = 0.f, s1 = 0.f, s2 = 0.f;
    #pragma unroll
    for (int cc = 0; cc < ICH / 4; cc++) {
        int c = q + cc * 4;
        const float* pp = p12 + ((size_t)wid * ICH + c) * 32;
        s1 += pp[h];
        s2 += pp[16 + h];
        s0 += p0[(size_t)wid * ICH + c];
    }
    s0 += __shfl_xor(s0, 16); s1 += __shfl_xor(s1, 16); s2 += __shfl_xor(s2, 16);
    s0 += __shfl_xor(s0, 32); s1 += __shfl_xor(s1, 32); s2 += __shfl_xor(s2, 32);

    // s1,s2 are in u-space (x2^16, x2^32); rescale here.
    float sumR = s0 + 1e-4f;
    float mu_s = s1 / sumR;                                   // mu * 2^16
    float varD = s2 - 2.f * mu_s * s1 + mu_s * mu_s * s0;     // u-space
    float var  = fmaxf(varD * INV_SCALE2 + EPSF * s0, 0.f);
    float sigsq = var / sumR + EPSF;
    float sig   = sqrtf(sigsq);
    float ls    = logf(sig + EPSF);
    float lssum = ls;
    lssum += __shfl_xor(lssum, 1);
    lssum += __shfl_xor(lssum, 2);
    lssum += __shfl_xor(lssum, 4);
    lssum += __shfl_xor(lssum, 8);
    const int c = j / 36;
    float cost = (16.f * beta_v[c] + lssum) * sumR;
    float aa   = 1.f / (1.f + expf(-1e-4f * (beta_a[c] - cost)));

    if (params) {
        if (q == 0) {
            float pi = 0.5f / sigsq;
            float* p = params + (size_t)wid * 48;
            p[h]      = mu_s;                                  // scaled mu
            p[16 + h] = pi * INV_SCALE2;                       // scaled inv2sig
            p[32 + h] = aa * 0.3989422804014327f / (sig + EPSF)
                        * __expf(-EPSF * pi);                  // eps term folded
        }
    } else {
        float* o = out_mua + (size_t)wid * HH;
        if (q == 0) o[h] = mu_s * INV_SCALE;
        if (lane == 16) o[16] = aa;
    }
}

__global__ __launch_bounds__(256) void estep_kernel(
    const unsigned short* __restrict__ vu16,
    const float* __restrict__ params,
    float* __restrict__ p_arr,           // p[b,i,j]
    float* __restrict__ psum)            // partial row sums [b,i,jt]
{
    __shared__ float wsum[4][ECH];
    const int x  = blockIdx.x;
    const int jt = x % JT;
    const int ic = (x / JT) % NECH;
    const int b  = x / (JT * NECH);
    const int t  = threadIdx.x;
    const int jl = t >> 2;
    const int h4 = t & 3;
    const int j  = jt * 64 + jl;
    const int i0 = ic * ECH;
    const int lane = t & 63, w = t >> 6;

    const float* pj4 = params + ((size_t)b * CWW + j) * 48 + h4 * 4;
    float4 pm = *(const float4*)(pj4);
    float4 pi = *(const float4*)(pj4 + 16);
    float4 pw = *(const float4*)(pj4 + 32);

    const size_t dbase = ((size_t)b * BKK + i0) * CWW + jt * 64 + jl;
    const unsigned short* vbase = vu16 + dbase * 16 + h4 * 4;

    #pragma unroll 4
    for (int i = 0; i < ECH; i++) {
        us4 u = *(const us4*)(vbase + (size_t)i * (CWW * 16));
        float d, pj = 0.f;
        d = (float)u.x - pm.x; pj += pw.x * __expf(-d * d * pi.x);
        d = (float)u.y - pm.y; pj += pw.y * __expf(-d * d * pi.y);
        d = (float)u.z - pm.z; pj += pw.z * __expf(-d * d * pi.z);
        d = (float)u.w - pm.w; pj += pw.w * __expf(-d * d * pi.w);
        pj += __shfl_xor(pj, 1);
        pj += __shfl_xor(pj, 2);
        if (h4 == 0)
            p_arr[dbase + (size_t)i * CWW] = pj;

        float rs = pj;
        rs += __shfl_xor(rs, 4);
        rs += __shfl_xor(rs, 8);
        rs += __shfl_xor(rs, 16);
        rs += __shfl_xor(rs, 32);
        if (lane == 0) wsum[w][i] = rs;
    }
    __syncthreads();
    if (t < ECH) {
        float s = wsum[0][t] + wsum[1][t] + wsum[2][t] + wsum[3][t];
        psum[((size_t)b * BKK + i0 + t) * JT + jt] = s;
    }
}

// streaming passthrough: NT load (votes stays un-reallocated, hits L3-warm
// lines) + NT store (never re-read). grid-stride, 2048 blocks.
__global__ __launch_bounds__(256) void copynt_kernel(
    const v4f* __restrict__ src, v4f* __restrict__ dst, int n)
{
    const int stride = gridDim.x * 256;
    for (int idx = blockIdx.x * 256 + threadIdx.x; idx < n; idx += stride) {
        v4f v = __builtin_nontemporal_load(src + idx);
        __builtin_nontemporal_store(v, dst + idx);
    }
}

extern "C" void kernel_launch(void* const* d_in, const int* in_sizes, int n_in,
                              void* d_out, int out_size, void* d_ws, size_t ws_size,
                              hipStream_t stream)
{
    const float* votes  = (const float*)d_in[0];
    const float* beta_v = (const float*)d_in[1];
    const float* beta_a = (const float*)d_in[2];
    float* out       = (float*)d_out;
    float* out_mua   = out;                                  // 8*1152*17
    float* out_R     = out + (size_t)NB * CWW * HH;          // 8*288*1152
    float* out_votes = out_R + (size_t)NB * BKK * CWW;

    const size_t n_p      = (size_t)NB * BKK * CWW;          // 2654208
    const size_t n_psum   = (size_t)NB * BKK * JT;
    const size_t n_p12    = (size_t)NB * CWW * ICH * 32;     // 4718592
    const size_t n_p0     = (size_t)NB * CWW * ICH;
    const size_t n_params = (size_t)NB * CWW * 48;
    const size_t n_f      = n_p + n_psum + n_p12 + n_p0 + n_params;
    const size_t n_vu     = (size_t)NB * BKK * CWW * 16;     // u16 count
    const size_t n_au     = (size_t)NB * BKK * CWW;          // u16 count
    const size_t need     = n_f * sizeof(float) + (n_vu + n_au) * sizeof(unsigned short);

    float* scr;
    bool fused;
    if (ws_size >= need) { scr = (float*)d_ws; fused = true; }
    else                 { scr = out_votes;    fused = false; }
    float* p_arr  = scr;
    float* psum   = p_arr + n_p;
    float* p12    = psum + n_psum;
    float* p0     = p12 + n_p12;
    float* params = p0 + n_p0;
    unsigned short* vu16 = (unsigned short*)(params + n_params);  // 8B-aligned
    unsigned short* au16 = vu16 + n_vu;

    dim3 blk(256);
    dim3 gmp(NB * ICH * JT);    // 2304
    dim3 gmf(NB * CWW / 4);     // 2304
    dim3 gea(NB * NECH * JT);   // 5184
    const int n4 = (int)((size_t)NB * BKK * CWW * HH / 4);   // 11280384

    // iter 0
    mpart0_kernel<<<gmp, blk, 0, stream>>>(votes, vu16, au16, p12, p0);
    if (fused)   // votes L3-warm right after mpart0's full read
        copynt_kernel<<<dim3(2048), blk, 0, stream>>>(
            (const v4f*)votes, (v4f*)out_votes, n4);
    mfin_kernel<<<gmf, blk, 0, stream>>>(p12, p0, beta_v, beta_a, params, nullptr);
    estep_kernel<<<gea, blk, 0, stream>>>(vu16, params, p_arr, psum);
    // iter 1 (rsinv computed inline from psum)
    mpart12_kernel<<<gmp, blk, 0, stream>>>(vu16, au16, p_arr, psum,
                                            p12, p0, nullptr);
    mfin_kernel<<<gmf, blk, 0, stream>>>(p12, p0, beta_v, beta_a, params, nullptr);
    estep_kernel<<<gea, blk, 0, stream>>>(vu16, params, p_arr, psum);
    // iter 2 (final; writes R_out = (p*rsinv+eps)*a_)
    mpart12_kernel<<<gmp, blk, 0, stream>>>(vu16, au16, p_arr, psum,
                                            p12, p0, out_R);
    mfin_kernel<<<gmf, blk, 0, stream>>>(p12, p0, beta_v, beta_a, nullptr, out_mua);

    if (!fused)  // scratch aliases out_votes: copy must be last
        copynt_kernel<<<dim3(2048), blk, 0, stream>>>(
            (const v4f*)votes, (v4f*)out_votes, n4);
}

// Round 4
// 440.884 us; speedup vs baseline: 1.0739x; 1.0739x over previous
//
#include <hip/hip_runtime.h>

#define NB   8
#define BKK  288
#define CWW  1152
#define HH   17
#define EPSF 1e-10f
#define ICH  16           // i-chunks for mpart partials
#define ISZ  18           // BKK/ICH
#define JT   18           // CWW/64 j-tiles
#define ECH  8            // i-rows per estep block
#define NECH 36           // BKK/ECH
#define SCALE      65536.f
#define INV_SCALE  (1.f/65536.f)
#define INV_SCALE2 (1.f/65536.f/65536.f)

// 4-aligned float4 (records are 17 floats; CDNA dwordx4 needs only dword align)
struct __attribute__((aligned(4))) f4u { float x, y, z, w; };
// 8-aligned ushort4 (vu16 records are 16 u16 = 32B, h4-chunks 8B-aligned)
struct __attribute__((aligned(8))) us4 { unsigned short x, y, z, w; };
typedef float v4f __attribute__((ext_vector_type(4)));

// params per (b,j): [0..15]=mu*2^16, [16..31]=(0.5/sigsq)*2^-32,
//                   [32..47]=a*rsqrt(2pi)/(sig+eps)*exp(-eps*0.5/sigsq)

// iter0 M-step: reads fp32 votes once; emits u16 votes + u16 a + partials +
// (fused) the passthrough copy. Explicit 2-stage software pipeline: all of
// iteration i+1's loads are issued before iteration i's math/stores, so each
// wave keeps ~4-8 global loads in flight (round-2 PMC showed VGPR=32,
// 2.5 TB/s, VALUBusy 8% => latency-bound at MLP~1).
__global__ __launch_bounds__(256, 4) void mpart0_kernel(
    const float* __restrict__ votes,
    unsigned short* __restrict__ vu16,
    unsigned short* __restrict__ au16,
    float* __restrict__ p12,
    float* __restrict__ p0,
    float* __restrict__ copy_dst)        // null => copynt at end (unfused)
{
    const int x  = blockIdx.x;
    const int jt = x % JT;
    const int c  = (x / JT) % ICH;
    const int b  = x / (JT * ICH);
    const int t  = threadIdx.x;
    const int jl = t >> 2;               // 0..63
    const int h4 = t & 3;
    const int i0 = c * ISZ;

    const size_t rowe = (size_t)CWW * HH;
    const float* base = votes + ((size_t)b * BKK + i0) * rowe + jt * (64 * HH);
    const int voff = jl * HH + h4 * 4;
    const int aoff = jl * HH + 16;
    const size_t dbase = ((size_t)b * BKK + i0) * CWW + jt * 64 + jl;

    const v4f* vt4 = (const v4f*)votes;
    v4f* ot4 = (v4f*)copy_dst;
    const size_t fb0  = (((size_t)b * BKK + i0) * rowe + (size_t)jt * (64 * HH)) >> 2;
    const size_t frow = rowe >> 2;       // 4896 v4f per record-row
    const bool docopy = (copy_dst != nullptr);
    const bool c1on   = (t < 16);        // 272 v4f per row: 256 + 16

    float s0 = 0.f;
    float s1x=0.f,s1y=0.f,s1z=0.f,s1w=0.f;
    float s2x=0.f,s2y=0.f,s2z=0.f,s2w=0.f;

    // prologue: loads for i = 0
    f4u  v_c = *(const f4u*)(base + voff);
    float a_c = base[aoff];
    v4f c0_c = {}, c1_c = {};
    if (docopy) {
        c0_c = vt4[fb0 + t];
        if (c1on) c1_c = vt4[fb0 + 256 + t];
    }

    for (int i = 0; i < ISZ; i++) {
        // issue next iteration's loads first (independent of cur's math)
        f4u v_n = {}; float a_n = 0.f; v4f c0_n = {}, c1_n = {};
        if (i + 1 < ISZ) {
            const float* rec2 = base + (size_t)(i + 1) * rowe;
            v_n = *(const f4u*)(rec2 + voff);
            a_n = rec2[aoff];
            if (docopy) {
                size_t fb = fb0 + (size_t)(i + 1) * frow;
                c0_n = vt4[fb + t];
                if (c1on) c1_n = vt4[fb + 256 + t];
            }
        }

        // u16 fixed-point quantize (error <= 2^-17; clamp avoids 65536 wrap)
        unsigned int ux = (unsigned int)(fminf(v_c.x * SCALE, 65535.f) + 0.5f);
        unsigned int uy = (unsigned int)(fminf(v_c.y * SCALE, 65535.f) + 0.5f);
        unsigned int uz = (unsigned int)(fminf(v_c.z * SCALE, 65535.f) + 0.5f);
        unsigned int uw = (unsigned int)(fminf(v_c.w * SCALE, 65535.f) + 0.5f);
        us4 us = { (unsigned short)ux, (unsigned short)uy,
                   (unsigned short)uz, (unsigned short)uw };
        *(us4*)(vu16 + (dbase + (size_t)i * CWW) * 16 + h4 * 4) = us;
        if (h4 == 0) {
            unsigned int ua = (unsigned int)(fminf(a_c * SCALE, 65535.f) + 0.5f);
            au16[dbase + (size_t)i * CWW] = (unsigned short)ua;
        }

        // accumulate in u-space (exact cvt; rescaled once in mfin)
        float fx = (float)ux, fy = (float)uy, fz = (float)uz, fw = (float)uw;
        float rt = a_c * (1.f / 32.f);
        s0 += rt;
        s1x += rt*fx; s2x += rt*fx*fx;
        s1y += rt*fy; s2y += rt*fy*fy;
        s1z += rt*fz; s2z += rt*fz*fz;
        s1w += rt*fw; s2w += rt*fw*fw;

        if (docopy) {   // L1-hot lines, NT store (never re-read)
            size_t fb = fb0 + (size_t)i * frow;
            __builtin_nontemporal_store(c0_c, ot4 + fb + t);
            if (c1on) __builtin_nontemporal_store(c1_c, ot4 + fb + 256 + t);
        }

        v_c = v_n; a_c = a_n; c0_c = c0_n; c1_c = c1_n;
    }

    const int j = jt * 64 + jl;
    float* o = p12 + (((size_t)(b * CWW + j)) * ICH + c) * 32 + h4 * 4;
    *(float4*)o        = make_float4(s1x, s1y, s1z, s1w);
    *(float4*)(o + 16) = make_float4(s2x, s2y, s2z, s2w);
    if (h4 == 0) p0[((size_t)(b * CWW + j)) * ICH + c] = s0;
}

// iters 1,2 M-step: u16 votes/a, inline rsinv from psum. Loads batched in
// chunks of 6 (18 loads in flight) before the accumulate block.
__global__ __launch_bounds__(256, 4) void mpart12_kernel(
    const unsigned short* __restrict__ vu16,
    const unsigned short* __restrict__ au16,
    const float* __restrict__ p_arr,
    const float* __restrict__ psum,      // [b,i,JT] partial row sums
    float* __restrict__ p12,
    float* __restrict__ p0,
    float* __restrict__ r_out)           // iter2: R_out = (p*rsinv+eps)*a_
{
    __shared__ float rsv[ISZ];
    const int x  = blockIdx.x;
    const int jt = x % JT;
    const int c  = (x / JT) % ICH;
    const int b  = x / (JT * ICH);
    const int t  = threadIdx.x;
    const int jl = t >> 2;
    const int h4 = t & 3;
    const int i0 = c * ISZ;
    const int bi0 = b * BKK + i0;

    if (t < ISZ) {
        const float* ps = psum + (size_t)(bi0 + t) * JT;
        float s = 0.f;
        #pragma unroll
        for (int k = 0; k < JT; k++) s += ps[k];
        rsv[t] = 1.f / (s + EPSF);
    }
    __syncthreads();

    const size_t dbase = (size_t)bi0 * CWW + jt * 64 + jl;
    const unsigned short* vbase = vu16 + dbase * 16 + h4 * 4;

    float s0 = 0.f;
    float s1x=0.f,s1y=0.f,s1z=0.f,s1w=0.f;
    float s2x=0.f,s2y=0.f,s2z=0.f,s2w=0.f;

    #pragma unroll
    for (int i6 = 0; i6 < ISZ; i6 += 6) {
        us4 u[6]; float pv[6]; float af[6];
        #pragma unroll
        for (int k = 0; k < 6; k++) {
            const int i = i6 + k;
            u[k]  = *(const us4*)(vbase + (size_t)i * (CWW * 16));
            pv[k] = p_arr[dbase + (size_t)i * CWW];
            af[k] = (float)au16[dbase + (size_t)i * CWW];
        }
        #pragma unroll
        for (int k = 0; k < 6; k++) {
            const int i = i6 + k;
            float av = af[k] * INV_SCALE;
            float rr = fmaf(pv[k], rsv[i], EPSF);   // R update (pre a_)
            float rt = rr * av;                     // reference's R*a_
            float fx = (float)u[k].x, fy = (float)u[k].y;
            float fz = (float)u[k].z, fw = (float)u[k].w;
            s0 += rt;
            s1x += rt*fx; s2x += rt*fx*fx;
            s1y += rt*fy; s2y += rt*fy*fy;
            s1z += rt*fz; s2z += rt*fz*fz;
            s1w += rt*fw; s2w += rt*fw*fw;
            // reference returns R after the top-of-iter2 reassignment:
            // (p*rsinv+eps)*a_
            if (r_out && h4 == 0)
                __builtin_nontemporal_store(rt, r_out + dbase + (size_t)i * CWW);
        }
    }

    const int j = jt * 64 + jl;
    float* o = p12 + (((size_t)(b * CWW + j)) * ICH + c) * 32 + h4 * 4;
    *(float4*)o        = make_float4(s1x, s1y, s1z, s1w);
    *(float4*)(o + 16) = make_float4(s2x, s2y, s2z, s2w);
    if (h4 == 0) p0[((size_t)(b * CWW + j)) * ICH + c] = s0;
}

__global__ __launch_bounds__(256) void mfin_kernel(
    const float* __restrict__ p12,
    const float* __restrict__ p0,
    const float* __restrict__ beta_v,
    const float* __restrict__ beta_a,
    float* __restrict__ params,          // non-final iters
    float* __restrict__ out_mua)         // final iter (params == null)
{
    const int wid  = (blockIdx.x * 256 + threadIdx.x) >> 6;   // b*1152+j
    const int lane = threadIdx.x & 63;
    const int h    = lane & 15;
    const int q    = lane >> 4;
    const int b    = wid / CWW;
    const int j    = wid - b * CWW;
    (void)b;

    float s0 = 0.f, s1 = 0.f, s2 = 0.f;
    #pragma unroll
    for (int cc = 0; cc < ICH / 4; cc++) {
        int c = q + cc * 4;
        const float* pp = p12 + ((size_t)wid * ICH + c) * 32;
        s1 += pp[h];
        s2 += pp[16 + h];
        s0 += p0[(size_t)wid * ICH + c];
    }
    s0 += __shfl_xor(s0, 16); s1 += __shfl_xor(s1, 16); s2 += __shfl_xor(s2, 16);
    s0 += __shfl_xor(s0, 32); s1 += __shfl_xor(s1, 32); s2 += __shfl_xor(s2, 32);

    // s1,s2 are in u-space (x2^16, x2^32); rescale here.
    float sumR = s0 + 1e-4f;
    float mu_s = s1 / sumR;                                   // mu * 2^16
    float varD = s2 - 2.f * mu_s * s1 + mu_s * mu_s * s0;     // u-space
    float var  = fmaxf(varD * INV_SCALE2 + EPSF * s0, 0.f);
    float sigsq = var / sumR + EPSF;
    float sig   = sqrtf(sigsq);
    float ls    = logf(sig + EPSF);
    float lssum = ls;
    lssum += __shfl_xor(lssum, 1);
    lssum += __shfl_xor(lssum, 2);
    lssum += __shfl_xor(lssum, 4);
    lssum += __shfl_xor(lssum, 8);
    const int c = j / 36;
    float cost = (16.f * beta_v[c] + lssum) * sumR;
    float aa   = 1.f / (1.f + expf(-1e-4f * (beta_a[c] - cost)));

    if (params) {
        if (q == 0) {
            float pi = 0.5f / sigsq;
            float* p = params + (size_t)wid * 48;
            p[h]      = mu_s;                                  // scaled mu
            p[16 + h] = pi * INV_SCALE2;                       // scaled inv2sig
            p[32 + h] = aa * 0.3989422804014327f / (sig + EPSF)
                        * __expf(-EPSF * pi);                  // eps term folded
        }
    } else {
        float* o = out_mua + (size_t)wid * HH;
        if (q == 0) o[h] = mu_s * INV_SCALE;
        if (lane == 16) o[16] = aa;
    }
}

// E-step: all ECH u16 loads batched into registers up-front (8 in flight),
// then the exp/shuffle compute loop.
__global__ __launch_bounds__(256, 4) void estep_kernel(
    const unsigned short* __restrict__ vu16,
    const float* __restrict__ params,
    float* __restrict__ p_arr,           // p[b,i,j]
    float* __restrict__ psum)            // partial row sums [b,i,jt]
{
    __shared__ float wsum[4][ECH];
    const int x  = blockIdx.x;
    const int jt = x % JT;
    const int ic = (x / JT) % NECH;
    const int b  = x / (JT * NECH);
    const int t  = threadIdx.x;
    const int jl = t >> 2;
    const int h4 = t & 3;
    const int j  = jt * 64 + jl;
    const int i0 = ic * ECH;
    const int lane = t & 63, w = t >> 6;

    const float* pj4 = params + ((size_t)b * CWW + j) * 48 + h4 * 4;
    float4 pm = *(const float4*)(pj4);
    float4 pi = *(const float4*)(pj4 + 16);
    float4 pw = *(const float4*)(pj4 + 32);

    const size_t dbase = ((size_t)b * BKK + i0) * CWW + jt * 64 + jl;
    const unsigned short* vbase = vu16 + dbase * 16 + h4 * 4;

    us4 u[ECH];
    #pragma unroll
    for (int i = 0; i < ECH; i++)
        u[i] = *(const us4*)(vbase + (size_t)i * (CWW * 16));

    #pragma unroll
    for (int i = 0; i < ECH; i++) {
        float d, pj = 0.f;
        d = (float)u[i].x - pm.x; pj += pw.x * __expf(-d * d * pi.x);
        d = (float)u[i].y - pm.y; pj += pw.y * __expf(-d * d * pi.y);
        d = (float)u[i].z - pm.z; pj += pw.z * __expf(-d * d * pi.z);
        d = (float)u[i].w - pm.w; pj += pw.w * __expf(-d * d * pi.w);
        pj += __shfl_xor(pj, 1);
        pj += __shfl_xor(pj, 2);
        if (h4 == 0)
            p_arr[dbase + (size_t)i * CWW] = pj;

        float rs = pj;
        rs += __shfl_xor(rs, 4);
        rs += __shfl_xor(rs, 8);
        rs += __shfl_xor(rs, 16);
        rs += __shfl_xor(rs, 32);
        if (lane == 0) wsum[w][i] = rs;
    }
    __syncthreads();
    if (t < ECH) {
        float s = wsum[0][t] + wsum[1][t] + wsum[2][t] + wsum[3][t];
        psum[((size_t)b * BKK + i0 + t) * JT + jt] = s;
    }
}

// streaming passthrough (unfused path only): cached load (L3 may be warm)
// + NT store. grid-stride, 2048 blocks.
__global__ __launch_bounds__(256) void copynt_kernel(
    const v4f* __restrict__ src, v4f* __restrict__ dst, int n)
{
    const int stride = gridDim.x * 256;
    for (int idx = blockIdx.x * 256 + threadIdx.x; idx < n; idx += stride) {
        v4f v = src[idx];
        __builtin_nontemporal_store(v, dst + idx);
    }
}

extern "C" void kernel_launch(void* const* d_in, const int* in_sizes, int n_in,
                              void* d_out, int out_size, void* d_ws, size_t ws_size,
                              hipStream_t stream)
{
    const float* votes  = (const float*)d_in[0];
    const float* beta_v = (const float*)d_in[1];
    const float* beta_a = (const float*)d_in[2];
    float* out       = (float*)d_out;
    float* out_mua   = out;                                  // 8*1152*17
    float* out_R     = out + (size_t)NB * CWW * HH;          // 8*288*1152
    float* out_votes = out_R + (size_t)NB * BKK * CWW;

    const size_t n_p      = (size_t)NB * BKK * CWW;          // 2654208
    const size_t n_psum   = (size_t)NB * BKK * JT;
    const size_t n_p12    = (size_t)NB * CWW * ICH * 32;     // 4718592
    const size_t n_p0     = (size_t)NB * CWW * ICH;
    const size_t n_params = (size_t)NB * CWW * 48;
    const size_t n_f      = n_p + n_psum + n_p12 + n_p0 + n_params;
    const size_t n_vu     = (size_t)NB * BKK * CWW * 16;     // u16 count
    const size_t n_au     = (size_t)NB * BKK * CWW;          // u16 count
    const size_t need     = n_f * sizeof(float) + (n_vu + n_au) * sizeof(unsigned short);

    float* scr;
    bool fused;
    if (ws_size >= need) { scr = (float*)d_ws; fused = true; }
    else                 { scr = out_votes;    fused = false; }
    float* p_arr  = scr;
    float* psum   = p_arr + n_p;
    float* p12    = psum + n_psum;
    float* p0     = p12 + n_p12;
    float* params = p0 + n_p0;
    unsigned short* vu16 = (unsigned short*)(params + n_params);  // 8B-aligned
    unsigned short* au16 = vu16 + n_vu;

    dim3 blk(256);
    dim3 gmp(NB * ICH * JT);    // 2304
    dim3 gmf(NB * CWW / 4);     // 2304
    dim3 gea(NB * NECH * JT);   // 5184
    const int n4 = (int)((size_t)NB * BKK * CWW * HH / 4);   // 11280384

    // iter 0 (copy fused when scratch doesn't alias out_votes)
    mpart0_kernel<<<gmp, blk, 0, stream>>>(votes, vu16, au16, p12, p0,
                                           fused ? out_votes : nullptr);
    mfin_kernel<<<gmf, blk, 0, stream>>>(p12, p0, beta_v, beta_a, params, nullptr);
    estep_kernel<<<gea, blk, 0, stream>>>(vu16, params, p_arr, psum);
    // iter 1 (rsinv computed inline from psum)
    mpart12_kernel<<<gmp, blk, 0, stream>>>(vu16, au16, p_arr, psum,
                                            p12, p0, nullptr);
    mfin_kernel<<<gmf, blk, 0, stream>>>(p12, p0, beta_v, beta_a, params, nullptr);
    estep_kernel<<<gea, blk, 0, stream>>>(vu16, params, p_arr, psum);
    // iter 2 (final; writes R_out = (p*rsinv+eps)*a_)
    mpart12_kernel<<<gmp, blk, 0, stream>>>(vu16, au16, p_arr, psum,
                                            p12, p0, out_R);
    mfin_kernel<<<gmf, blk, 0, stream>>>(p12, p0, beta_v, beta_a, nullptr, out_mua);

    if (!fused)  // scratch aliases out_votes: copy must be last
        copynt_kernel<<<dim3(2048), blk, 0, stream>>>(
            (const v4f*)votes, (v4f*)out_votes, n4);
}